// Round 3
// baseline (1197.569 us; speedup 1.0000x reference)
//
#include <hip/hip_runtime.h>

#define NN 50000
#define NE 800000

typedef __bf16 bf16_t;
typedef __bf16 bf16x8 __attribute__((ext_vector_type(8)));
typedef float f32x4 __attribute__((ext_vector_type(4)));

// ---- workspace layout (bytes) ----
// shared weights region
#define W1A_OFF 0
#define W1A_B (256 * 256 * 2)
#define W1B_OFF (W1A_OFF + W1A_B)
#define W1B_B (128 * 256 * 2)
#define W2A_OFF (W1B_OFF + W1B_B)
#define W2A_B (256 * 384 * 2)
#define W2B_OFF (W2A_OFF + W2A_B)
#define W2B_B (128 * 256 * 2)
#define WEND (W2B_OFF + W2B_B)
// CSR path
#define NSCAN_BLOCKS ((NN + 255) / 256)
#define BASE_OFF WEND
#define BASE_B (((NN + 1 + 63) / 64) * 64 * 4)   // base[0..NN]
#define BSUM_OFF (BASE_OFF + BASE_B)
#define BSUM_B (256 * 4)                          // dedicated: 196 < 256 blocks
#define OFF_OFF (BSUM_OFF + BSUM_B)
#define OFF_B (NN * 4)
#define CNT2_OFF (OFF_OFF + OFF_B)
#define CNT2_B (NN * 4)
#define PERM_OFF (CNT2_OFF + CNT2_B)
#define PERM_B (NE * 4)
#define HBUF_OFF (((PERM_OFF + PERM_B) + 255) / 256 * 256)
#define HBUF_B (NE * 128 * 2)
#define CSR_NEED ((size_t)(HBUF_OFF + HBUF_B))
// atomic fallback path
#define SUM_OFF WEND
#define SUM_B (NN * 128 * 4)
#define ACNT_OFF (SUM_OFF + SUM_B)
#define ACNT_B (NN * 4)

// Convert W[k][n] (row-major [K][Nn] fp32) -> Wt[n][k] bf16 (k contiguous).
__global__ __launch_bounds__(256) void transpose_bf16(
    const float* __restrict__ src, bf16_t* __restrict__ dst, int K, int Nn) {
  int idx = blockIdx.x * 256 + threadIdx.x;
  if (idx >= K * Nn) return;
  int n = idx / K;
  int k = idx - n * K;
  dst[idx] = (bf16_t)src[k * Nn + n];
}

// ================= CSR construction =================
__global__ __launch_bounds__(256) void hist_kernel(
    const int* __restrict__ ei, int* __restrict__ cnt) {
  int e = blockIdx.x * 256 + threadIdx.x;
  if (e < NE) atomicAdd(&cnt[ei[NE + e]], 1);
}

__global__ __launch_bounds__(256) void scan1(
    const int* __restrict__ cnt, int* __restrict__ base, int* __restrict__ bsum) {
  __shared__ int s[256];
  const int tid = threadIdx.x;
  const int g = blockIdx.x * 256 + tid;
  int v = (g < NN) ? cnt[g] : 0;
  s[tid] = v;
  __syncthreads();
#pragma unroll
  for (int o = 1; o < 256; o <<= 1) {
    int t = (tid >= o) ? s[tid - o] : 0;
    __syncthreads();
    s[tid] += t;
    __syncthreads();
  }
  if (g < NN) base[g] = s[tid] - v;  // block-local exclusive
  if (tid == 255) bsum[blockIdx.x] = s[255];
}

__global__ __launch_bounds__(256) void scan2(int* __restrict__ bsum, int nb) {
  __shared__ int s[256];
  const int tid = threadIdx.x;
  int v = (tid < nb) ? bsum[tid] : 0;
  s[tid] = v;
  __syncthreads();
#pragma unroll
  for (int o = 1; o < 256; o <<= 1) {
    int t = (tid >= o) ? s[tid - o] : 0;
    __syncthreads();
    s[tid] += t;
    __syncthreads();
  }
  if (tid < nb) bsum[tid] = s[tid] - v;  // exclusive block offsets
}

__global__ __launch_bounds__(256) void scan3(
    int* __restrict__ base, const int* __restrict__ bsum, int* __restrict__ off) {
  int g = blockIdx.x * 256 + threadIdx.x;
  if (g < NN) {
    int b = base[g] + bsum[g >> 8];
    base[g] = b;
    off[g] = b;
  } else if (g == NN) {
    base[NN] = NE;
  }
}

__global__ __launch_bounds__(256) void slot_kernel(
    const int* __restrict__ ei, int* __restrict__ off, int* __restrict__ perm) {
  int e = blockIdx.x * 256 + threadIdx.x;
  if (e < NE) {
    int p = atomicAdd(&off[ei[NE + e]], 1);
    perm[p] = e;
  }
}

// ================= CSR edge MLP: h[e] = mlp1([x[row]|ea]) -> hbuf (bf16) ======
__global__ __launch_bounds__(256) void edge_mlp_csr(
    const float* __restrict__ x, const int* __restrict__ ei,
    const float* __restrict__ ea,
    const bf16_t* __restrict__ Wt1a, const float* __restrict__ b1a,
    const bf16_t* __restrict__ Wt1b, const float* __restrict__ b1b,
    bf16_t* __restrict__ hbuf) {
  __shared__ __align__(16) bf16_t As[64][264];
  __shared__ int rowS[64];
  const int tid = threadIdx.x;
  const int lane = tid & 63;
  const int wave = tid >> 6;
  const int e0 = blockIdx.x * 64;

  if (tid < 64) rowS[tid] = ei[e0 + tid];
  __syncthreads();

  // stage A = [x[row] | edge_attr] bf16
  {
    const int t_in = tid & 63;
    const int esub = tid >> 6;
    const int c0 = t_in * 4;
#pragma unroll
    for (int it = 0; it < 16; ++it) {
      const int i = it * 4 + esub;
      float4 f;
      if (c0 < 128) {
        f = *(const float4*)(x + rowS[i] * 128 + c0);
      } else {
        f = *(const float4*)(ea + (e0 + i) * 128 + (c0 - 128));
      }
      union { bf16_t h[4]; uint2 u; } pk;
      pk.h[0] = (bf16_t)f.x; pk.h[1] = (bf16_t)f.y;
      pk.h[2] = (bf16_t)f.z; pk.h[3] = (bf16_t)f.w;
      *(uint2*)&As[i][c0] = pk.u;
    }
  }
  __syncthreads();

  const int lr = lane & 15;
  const int lq = lane >> 4;

  // layer 1: hidden(64x256) = relu(A @ W1a + b1a); wave owns 64 cols
  const int n_off = wave * 64;
  float bias1[4];
#pragma unroll
  for (int nt = 0; nt < 4; ++nt) bias1[nt] = b1a[n_off + nt * 16 + lr];

  f32x4 acc[4][4];
#pragma unroll
  for (int mt = 0; mt < 4; ++mt)
#pragma unroll
    for (int nt = 0; nt < 4; ++nt) acc[mt][nt] = (f32x4){0.f, 0.f, 0.f, 0.f};

#pragma unroll
  for (int ks = 0; ks < 8; ++ks) {
    const int k0 = ks * 32 + lq * 8;
    bf16x8 af[4], bv[4];
#pragma unroll
    for (int mt = 0; mt < 4; ++mt)
      af[mt] = *(const bf16x8*)&As[mt * 16 + lr][k0];
#pragma unroll
    for (int nt = 0; nt < 4; ++nt)
      bv[nt] = *(const bf16x8*)&Wt1a[(n_off + nt * 16 + lr) * 256 + k0];
#pragma unroll
    for (int mt = 0; mt < 4; ++mt)
#pragma unroll
      for (int nt = 0; nt < 4; ++nt)
        acc[mt][nt] = __builtin_amdgcn_mfma_f32_16x16x32_bf16(
            af[mt], bv[nt], acc[mt][nt], 0, 0, 0);
  }
  __syncthreads();
#pragma unroll
  for (int mt = 0; mt < 4; ++mt)
#pragma unroll
    for (int nt = 0; nt < 4; ++nt) {
      const int row = mt * 16 + lq * 4;
      const int colF = n_off + nt * 16 + lr;
#pragma unroll
      for (int r = 0; r < 4; ++r) {
        float v = acc[mt][nt][r] + bias1[nt];
        As[row + r][colF] = (bf16_t)fmaxf(v, 0.f);
      }
    }
  __syncthreads();

  // layer 2: out(64x128) = hidden @ W1b + b1b; wave owns 32 cols
  const int n2 = wave * 32;
  float bias2[2];
#pragma unroll
  for (int nt = 0; nt < 2; ++nt) bias2[nt] = b1b[n2 + nt * 16 + lr];

  f32x4 acc2[4][2];
#pragma unroll
  for (int mt = 0; mt < 4; ++mt)
#pragma unroll
    for (int nt = 0; nt < 2; ++nt) acc2[mt][nt] = (f32x4){0.f, 0.f, 0.f, 0.f};

#pragma unroll
  for (int ks = 0; ks < 8; ++ks) {
    const int k0 = ks * 32 + lq * 8;
    bf16x8 af[4], bv[2];
#pragma unroll
    for (int mt = 0; mt < 4; ++mt)
      af[mt] = *(const bf16x8*)&As[mt * 16 + lr][k0];
#pragma unroll
    for (int nt = 0; nt < 2; ++nt)
      bv[nt] = *(const bf16x8*)&Wt1b[(n2 + nt * 16 + lr) * 256 + k0];
#pragma unroll
    for (int mt = 0; mt < 4; ++mt)
#pragma unroll
      for (int nt = 0; nt < 2; ++nt)
        acc2[mt][nt] = __builtin_amdgcn_mfma_f32_16x16x32_bf16(
            af[mt], bv[nt], acc2[mt][nt], 0, 0, 0);
  }
  __syncthreads();  // all waves done reading hidden in As

  // write h (bf16) into As cols 0..127
#pragma unroll
  for (int mt = 0; mt < 4; ++mt)
#pragma unroll
    for (int nt = 0; nt < 2; ++nt) {
      const int colF = n2 + nt * 16 + lr;
#pragma unroll
      for (int r = 0; r < 4; ++r) {
        const int row = mt * 16 + lq * 4 + r;
        As[row][colF] = (bf16_t)(acc2[mt][nt][r] + bias2[nt]);
      }
    }
  __syncthreads();

  // coalesced vector store: 4 threads per row, 64B each
  {
    const int i = tid >> 2;
    const int q = tid & 3;
    const uint4* src = (const uint4*)&As[i][q * 32];
    uint4* dst = (uint4*)(hbuf + (size_t)(e0 + i) * 128 + q * 32);
    uint4 a0 = src[0], a1 = src[1], a2 = src[2], a3 = src[3];
    dst[0] = a0; dst[1] = a1; dst[2] = a2; dst[3] = a3;
  }
}

// ===== CSR node MLP: gather bucket, mean, then mlp2([x|agg|u[batch]]) =====
__global__ __launch_bounds__(256) void node_mlp_csr(
    const float* __restrict__ x, const float* __restrict__ u,
    const int* __restrict__ batch,
    const bf16_t* __restrict__ Wt2a, const float* __restrict__ b2a,
    const bf16_t* __restrict__ Wt2b, const float* __restrict__ b2b,
    const bf16_t* __restrict__ hbuf, const int* __restrict__ base,
    const int* __restrict__ perm, float* __restrict__ out) {
  __shared__ __align__(16) bf16_t As[64][392];
  __shared__ int bS[64], bE[64];
  const int tid = threadIdx.x;
  const int lane = tid & 63;
  const int wave = tid >> 6;
  const int n0 = blockIdx.x * 64;

  if (tid < 64) {
    int n = n0 + tid;
    bS[tid] = (n < NN) ? base[n] : 0;
    bE[tid] = (n < NN) ? base[n + 1] : 0;
  }
  __syncthreads();

  // stage x cols 0..127
  for (int v = tid; v < 64 * 32; v += 256) {
    const int i = v >> 5;
    const int c0 = (v & 31) * 4;
    const int n = n0 + i;
    float4 f = make_float4(0.f, 0.f, 0.f, 0.f);
    if (n < NN) f = *(const float4*)(x + n * 128 + c0);
    union { bf16_t h[4]; uint2 uu; } pk;
    pk.h[0] = (bf16_t)f.x; pk.h[1] = (bf16_t)f.y;
    pk.h[2] = (bf16_t)f.z; pk.h[3] = (bf16_t)f.w;
    *(uint2*)&As[i][c0] = pk.uu;
  }
  // stage u[batch] cols 256..383
  for (int v = tid; v < 64 * 32; v += 256) {
    const int i = v >> 5;
    const int c0 = (v & 31) * 4;
    const int n = n0 + i;
    float4 f = make_float4(0.f, 0.f, 0.f, 0.f);
    if (n < NN) f = *(const float4*)(u + batch[n] * 128 + c0);
    union { bf16_t h[4]; uint2 uu; } pk;
    pk.h[0] = (bf16_t)f.x; pk.h[1] = (bf16_t)f.y;
    pk.h[2] = (bf16_t)f.z; pk.h[3] = (bf16_t)f.w;
    *(uint2*)&As[i][256 + c0] = pk.uu;
  }
  // aggregate bucket -> agg cols 128..255 ; thread = (node i, col-chunk q)
  {
    const int i = tid >> 2;
    const int q = tid & 3;
    float acc[32];
#pragma unroll
    for (int c = 0; c < 32; ++c) acc[c] = 0.f;
    const int jb = bS[i], je = bE[i];
    for (int j = jb; j < je; ++j) {
      const int e = perm[j];
      if ((unsigned)e >= NE) continue;  // defensive: poison -> absmax, not abort
      const bf16x8* hp = (const bf16x8*)(hbuf + (size_t)e * 128 + q * 32);
#pragma unroll
      for (int v = 0; v < 4; ++v) {
        bf16x8 hv = hp[v];
#pragma unroll
        for (int c = 0; c < 8; ++c) acc[v * 8 + c] += (float)hv[c];
      }
    }
    const float inv = 1.0f / fmaxf((float)(je - jb), 1.0f);
#pragma unroll
    for (int c = 0; c < 32; ++c)
      As[i][128 + q * 32 + c] = (bf16_t)(acc[c] * inv);
  }
  __syncthreads();

  const int lr = lane & 15;
  const int lq = lane >> 4;

  // layer 1: hidden(64x256) = relu(z @ W2a + b2a)
  const int n_off = wave * 64;
  float bias1[4];
#pragma unroll
  for (int nt = 0; nt < 4; ++nt) bias1[nt] = b2a[n_off + nt * 16 + lr];

  f32x4 acc[4][4];
#pragma unroll
  for (int mt = 0; mt < 4; ++mt)
#pragma unroll
    for (int nt = 0; nt < 4; ++nt) acc[mt][nt] = (f32x4){0.f, 0.f, 0.f, 0.f};

#pragma unroll
  for (int ks = 0; ks < 12; ++ks) {
    const int k0 = ks * 32 + lq * 8;
    bf16x8 af[4], bv[4];
#pragma unroll
    for (int mt = 0; mt < 4; ++mt)
      af[mt] = *(const bf16x8*)&As[mt * 16 + lr][k0];
#pragma unroll
    for (int nt = 0; nt < 4; ++nt)
      bv[nt] = *(const bf16x8*)&Wt2a[(n_off + nt * 16 + lr) * 384 + k0];
#pragma unroll
    for (int mt = 0; mt < 4; ++mt)
#pragma unroll
      for (int nt = 0; nt < 4; ++nt)
        acc[mt][nt] = __builtin_amdgcn_mfma_f32_16x16x32_bf16(
            af[mt], bv[nt], acc[mt][nt], 0, 0, 0);
  }
  __syncthreads();
#pragma unroll
  for (int mt = 0; mt < 4; ++mt)
#pragma unroll
    for (int nt = 0; nt < 4; ++nt) {
      const int row = mt * 16 + lq * 4;
      const int colF = n_off + nt * 16 + lr;
#pragma unroll
      for (int r = 0; r < 4; ++r) {
        float v = acc[mt][nt][r] + bias1[nt];
        As[row + r][colF] = (bf16_t)fmaxf(v, 0.f);
      }
    }
  __syncthreads();

  // layer 2: out(64x128) = hidden @ W2b + b2b
  const int n2 = wave * 32;
  float bias2[2];
#pragma unroll
  for (int nt = 0; nt < 2; ++nt) bias2[nt] = b2b[n2 + nt * 16 + lr];

  f32x4 acc2[4][2];
#pragma unroll
  for (int mt = 0; mt < 4; ++mt)
#pragma unroll
    for (int nt = 0; nt < 2; ++nt) acc2[mt][nt] = (f32x4){0.f, 0.f, 0.f, 0.f};

#pragma unroll
  for (int ks = 0; ks < 8; ++ks) {
    const int k0 = ks * 32 + lq * 8;
    bf16x8 af[4], bv[2];
#pragma unroll
    for (int mt = 0; mt < 4; ++mt)
      af[mt] = *(const bf16x8*)&As[mt * 16 + lr][k0];
#pragma unroll
    for (int nt = 0; nt < 2; ++nt)
      bv[nt] = *(const bf16x8*)&Wt2b[(n2 + nt * 16 + lr) * 256 + k0];
#pragma unroll
    for (int mt = 0; mt < 4; ++mt)
#pragma unroll
      for (int nt = 0; nt < 2; ++nt)
        acc2[mt][nt] = __builtin_amdgcn_mfma_f32_16x16x32_bf16(
            af[mt], bv[nt], acc2[mt][nt], 0, 0, 0);
  }

#pragma unroll
  for (int mt = 0; mt < 4; ++mt)
#pragma unroll
    for (int nt = 0; nt < 2; ++nt) {
      const int colF = n2 + nt * 16 + lr;
#pragma unroll
      for (int r = 0; r < 4; ++r) {
        const int row = mt * 16 + lq * 4 + r;
        const int n = n0 + row;
        if (n < NN) out[n * 128 + colF] = acc2[mt][nt][r] + bias2[nt];
      }
    }
}

// ================= atomic fallback path (round-1 kernels) =================
__global__ __launch_bounds__(256) void edge_mlp_atomic(
    const float* __restrict__ x, const int* __restrict__ ei,
    const float* __restrict__ ea,
    const bf16_t* __restrict__ Wt1a, const float* __restrict__ b1a,
    const bf16_t* __restrict__ Wt1b, const float* __restrict__ b1b,
    float* __restrict__ sum, float* __restrict__ cnt) {
  __shared__ __align__(16) bf16_t As[64][264];
  __shared__ int rowS[64];
  __shared__ int colS[64];
  const int tid = threadIdx.x;
  const int lane = tid & 63;
  const int wave = tid >> 6;
  const int e0 = blockIdx.x * 64;

  if (tid < 64) {
    rowS[tid] = ei[e0 + tid];
    int c = ei[NE + e0 + tid];
    colS[tid] = c;
    atomicAdd(&cnt[c], 1.0f);
  }
  __syncthreads();
  {
    const int t_in = tid & 63;
    const int esub = tid >> 6;
    const int c0 = t_in * 4;
#pragma unroll
    for (int it = 0; it < 16; ++it) {
      const int i = it * 4 + esub;
      float4 f;
      if (c0 < 128) f = *(const float4*)(x + rowS[i] * 128 + c0);
      else f = *(const float4*)(ea + (e0 + i) * 128 + (c0 - 128));
      union { bf16_t h[4]; uint2 u; } pk;
      pk.h[0] = (bf16_t)f.x; pk.h[1] = (bf16_t)f.y;
      pk.h[2] = (bf16_t)f.z; pk.h[3] = (bf16_t)f.w;
      *(uint2*)&As[i][c0] = pk.u;
    }
  }
  __syncthreads();
  const int lr = lane & 15;
  const int lq = lane >> 4;
  const int n_off = wave * 64;
  float bias1[4];
#pragma unroll
  for (int nt = 0; nt < 4; ++nt) bias1[nt] = b1a[n_off + nt * 16 + lr];
  f32x4 acc[4][4];
#pragma unroll
  for (int mt = 0; mt < 4; ++mt)
#pragma unroll
    for (int nt = 0; nt < 4; ++nt) acc[mt][nt] = (f32x4){0.f, 0.f, 0.f, 0.f};
#pragma unroll
  for (int ks = 0; ks < 8; ++ks) {
    const int k0 = ks * 32 + lq * 8;
    bf16x8 af[4], bv[4];
#pragma unroll
    for (int mt = 0; mt < 4; ++mt) af[mt] = *(const bf16x8*)&As[mt * 16 + lr][k0];
#pragma unroll
    for (int nt = 0; nt < 4; ++nt)
      bv[nt] = *(const bf16x8*)&Wt1a[(n_off + nt * 16 + lr) * 256 + k0];
#pragma unroll
    for (int mt = 0; mt < 4; ++mt)
#pragma unroll
      for (int nt = 0; nt < 4; ++nt)
        acc[mt][nt] = __builtin_amdgcn_mfma_f32_16x16x32_bf16(
            af[mt], bv[nt], acc[mt][nt], 0, 0, 0);
  }
  __syncthreads();
#pragma unroll
  for (int mt = 0; mt < 4; ++mt)
#pragma unroll
    for (int nt = 0; nt < 4; ++nt) {
      const int row = mt * 16 + lq * 4;
      const int colF = n_off + nt * 16 + lr;
#pragma unroll
      for (int r = 0; r < 4; ++r) {
        float v = acc[mt][nt][r] + bias1[nt];
        As[row + r][colF] = (bf16_t)fmaxf(v, 0.f);
      }
    }
  __syncthreads();
  const int n2 = wave * 32;
  float bias2[2];
#pragma unroll
  for (int nt = 0; nt < 2; ++nt) bias2[nt] = b1b[n2 + nt * 16 + lr];
  f32x4 acc2[4][2];
#pragma unroll
  for (int mt = 0; mt < 4; ++mt)
#pragma unroll
    for (int nt = 0; nt < 2; ++nt) acc2[mt][nt] = (f32x4){0.f, 0.f, 0.f, 0.f};
#pragma unroll
  for (int ks = 0; ks < 8; ++ks) {
    const int k0 = ks * 32 + lq * 8;
    bf16x8 af[4], bv[2];
#pragma unroll
    for (int mt = 0; mt < 4; ++mt) af[mt] = *(const bf16x8*)&As[mt * 16 + lr][k0];
#pragma unroll
    for (int nt = 0; nt < 2; ++nt)
      bv[nt] = *(const bf16x8*)&Wt1b[(n2 + nt * 16 + lr) * 256 + k0];
#pragma unroll
    for (int mt = 0; mt < 4; ++mt)
#pragma unroll
      for (int nt = 0; nt < 2; ++nt)
        acc2[mt][nt] = __builtin_amdgcn_mfma_f32_16x16x32_bf16(
            af[mt], bv[nt], acc2[mt][nt], 0, 0, 0);
  }
#pragma unroll
  for (int mt = 0; mt < 4; ++mt)
#pragma unroll
    for (int nt = 0; nt < 2; ++nt) {
      const int colF = n2 + nt * 16 + lr;
#pragma unroll
      for (int r = 0; r < 4; ++r) {
        const int row = mt * 16 + lq * 4 + r;
        atomicAdd(&sum[colS[row] * 128 + colF], acc2[mt][nt][r] + bias2[nt]);
      }
    }
}

__global__ __launch_bounds__(256) void node_mlp_atomic(
    const float* __restrict__ x, const float* __restrict__ u,
    const int* __restrict__ batch,
    const bf16_t* __restrict__ Wt2a, const float* __restrict__ b2a,
    const bf16_t* __restrict__ Wt2b, const float* __restrict__ b2b,
    const float* __restrict__ sum, const float* __restrict__ cnt,
    float* __restrict__ out) {
  __shared__ __align__(16) bf16_t As[64][392];
  const int tid = threadIdx.x;
  const int lane = tid & 63;
  const int wave = tid >> 6;
  const int n0 = blockIdx.x * 64;
  for (int v = tid; v < 64 * 96; v += 256) {
    const int i = v / 96;
    const int seg = v - i * 96;
    const int c0 = seg * 4;
    const int n = n0 + i;
    float4 f = make_float4(0.f, 0.f, 0.f, 0.f);
    if (n < NN) {
      if (c0 < 128) f = *(const float4*)(x + n * 128 + c0);
      else if (c0 < 256) {
        const float inv = 1.0f / fmaxf(cnt[n], 1.0f);
        float4 s = *(const float4*)(sum + n * 128 + (c0 - 128));
        f = make_float4(s.x * inv, s.y * inv, s.z * inv, s.w * inv);
      } else {
        f = *(const float4*)(u + batch[n] * 128 + (c0 - 256));
      }
    }
    union { bf16_t h[4]; uint2 uu; } pk;
    pk.h[0] = (bf16_t)f.x; pk.h[1] = (bf16_t)f.y;
    pk.h[2] = (bf16_t)f.z; pk.h[3] = (bf16_t)f.w;
    *(uint2*)&As[i][c0] = pk.uu;
  }
  __syncthreads();
  const int lr = lane & 15;
  const int lq = lane >> 4;
  const int n_off = wave * 64;
  float bias1[4];
#pragma unroll
  for (int nt = 0; nt < 4; ++nt) bias1[nt] = b2a[n_off + nt * 16 + lr];
  f32x4 acc[4][4];
#pragma unroll
  for (int mt = 0; mt < 4; ++mt)
#pragma unroll
    for (int nt = 0; nt < 4; ++nt) acc[mt][nt] = (f32x4){0.f, 0.f, 0.f, 0.f};
#pragma unroll
  for (int ks = 0; ks < 12; ++ks) {
    const int k0 = ks * 32 + lq * 8;
    bf16x8 af[4], bv[4];
#pragma unroll
    for (int mt = 0; mt < 4; ++mt) af[mt] = *(const bf16x8*)&As[mt * 16 + lr][k0];
#pragma unroll
    for (int nt = 0; nt < 4; ++nt)
      bv[nt] = *(const bf16x8*)&Wt2a[(n_off + nt * 16 + lr) * 384 + k0];
#pragma unroll
    for (int mt = 0; mt < 4; ++mt)
#pragma unroll
      for (int nt = 0; nt < 4; ++nt)
        acc[mt][nt] = __builtin_amdgcn_mfma_f32_16x16x32_bf16(
            af[mt], bv[nt], acc[mt][nt], 0, 0, 0);
  }
  __syncthreads();
#pragma unroll
  for (int mt = 0; mt < 4; ++mt)
#pragma unroll
    for (int nt = 0; nt < 4; ++nt) {
      const int row = mt * 16 + lq * 4;
      const int colF = n_off + nt * 16 + lr;
#pragma unroll
      for (int r = 0; r < 4; ++r) {
        float v = acc[mt][nt][r] + bias1[nt];
        As[row + r][colF] = (bf16_t)fmaxf(v, 0.f);
      }
    }
  __syncthreads();
  const int n2 = wave * 32;
  float bias2[2];
#pragma unroll
  for (int nt = 0; nt < 2; ++nt) bias2[nt] = b2b[n2 + nt * 16 + lr];
  f32x4 acc2[4][2];
#pragma unroll
  for (int mt = 0; mt < 4; ++mt)
#pragma unroll
    for (int nt = 0; nt < 2; ++nt) acc2[mt][nt] = (f32x4){0.f, 0.f, 0.f, 0.f};
#pragma unroll
  for (int ks = 0; ks < 8; ++ks) {
    const int k0 = ks * 32 + lq * 8;
    bf16x8 af[4], bv[2];
#pragma unroll
    for (int mt = 0; mt < 4; ++mt) af[mt] = *(const bf16x8*)&As[mt * 16 + lr][k0];
#pragma unroll
    for (int nt = 0; nt < 2; ++nt)
      bv[nt] = *(const bf16x8*)&Wt2b[(n2 + nt * 16 + lr) * 256 + k0];
#pragma unroll
    for (int mt = 0; mt < 4; ++mt)
#pragma unroll
      for (int nt = 0; nt < 2; ++nt)
        acc2[mt][nt] = __builtin_amdgcn_mfma_f32_16x16x32_bf16(
            af[mt], bv[nt], acc2[mt][nt], 0, 0, 0);
  }
#pragma unroll
  for (int mt = 0; mt < 4; ++mt)
#pragma unroll
    for (int nt = 0; nt < 2; ++nt) {
      const int colF = n2 + nt * 16 + lr;
#pragma unroll
      for (int r = 0; r < 4; ++r) {
        const int row = mt * 16 + lq * 4 + r;
        const int n = n0 + row;
        if (n < NN) out[n * 128 + colF] = acc2[mt][nt][r] + bias2[nt];
      }
    }
}

extern "C" void kernel_launch(void* const* d_in, const int* in_sizes, int n_in,
                              void* d_out, int out_size, void* d_ws, size_t ws_size,
                              hipStream_t stream) {
  const float* x    = (const float*)d_in[0];
  const int*   ei   = (const int*)d_in[1];
  const float* ea   = (const float*)d_in[2];
  const float* u    = (const float*)d_in[3];
  const int*   batch= (const int*)d_in[4];
  const float* W1a  = (const float*)d_in[5];
  const float* b1a  = (const float*)d_in[6];
  const float* W1b  = (const float*)d_in[7];
  const float* b1b  = (const float*)d_in[8];
  const float* W2a  = (const float*)d_in[9];
  const float* b2a  = (const float*)d_in[10];
  const float* W2b  = (const float*)d_in[11];
  const float* b2b  = (const float*)d_in[12];

  char* ws = (char*)d_ws;
  bf16_t* w1a = (bf16_t*)(ws + W1A_OFF);
  bf16_t* w1b = (bf16_t*)(ws + W1B_OFF);
  bf16_t* w2a = (bf16_t*)(ws + W2A_OFF);
  bf16_t* w2b = (bf16_t*)(ws + W2B_OFF);

  transpose_bf16<<<256, 256, 0, stream>>>(W1a, w1a, 256, 256);
  transpose_bf16<<<128, 256, 0, stream>>>(W1b, w1b, 256, 128);
  transpose_bf16<<<384, 256, 0, stream>>>(W2a, w2a, 384, 256);
  transpose_bf16<<<128, 256, 0, stream>>>(W2b, w2b, 256, 128);

  if (ws_size >= CSR_NEED) {
    int* base = (int*)(ws + BASE_OFF);
    int* bsum = (int*)(ws + BSUM_OFF);
    int* off  = (int*)(ws + OFF_OFF);
    int* cnt  = (int*)(ws + CNT2_OFF);
    int* perm = (int*)(ws + PERM_OFF);
    bf16_t* hbuf = (bf16_t*)(ws + HBUF_OFF);

    hipMemsetAsync(cnt, 0, CNT2_B, stream);
    hist_kernel<<<(NE + 255) / 256, 256, 0, stream>>>(ei, cnt);
    scan1<<<NSCAN_BLOCKS, 256, 0, stream>>>(cnt, base, bsum);
    scan2<<<1, 256, 0, stream>>>(bsum, NSCAN_BLOCKS);
    scan3<<<(NN + 256) / 256, 256, 0, stream>>>(base, bsum, off);
    slot_kernel<<<(NE + 255) / 256, 256, 0, stream>>>(ei, off, perm);
    edge_mlp_csr<<<NE / 64, 256, 0, stream>>>(x, ei, ea, w1a, b1a, w1b, b1b, hbuf);
    node_mlp_csr<<<(NN + 63) / 64, 256, 0, stream>>>(
        x, u, batch, w2a, b2a, w2b, b2b, hbuf, base, perm, (float*)d_out);
  } else {
    float* sum = (float*)(ws + SUM_OFF);
    float* cnt = (float*)(ws + ACNT_OFF);
    hipMemsetAsync(ws + SUM_OFF, 0, SUM_B + ACNT_B, stream);
    edge_mlp_atomic<<<NE / 64, 256, 0, stream>>>(x, ei, ea, w1a, b1a, w1b, b1b,
                                                 sum, cnt);
    node_mlp_atomic<<<(NN + 63) / 64, 256, 0, stream>>>(
        x, u, batch, w2a, b2a, w2b, b2b, sum, cnt, (float*)d_out);
  }
}

// Round 4
// 1068.652 us; speedup vs baseline: 1.1206x; 1.1206x over previous
//
#include <hip/hip_runtime.h>

#define NN 50000
#define NE 800000

typedef __bf16 bf16_t;
typedef __bf16 bf16x8 __attribute__((ext_vector_type(8)));
typedef float f32x4 __attribute__((ext_vector_type(4)));

// ---- workspace layout (bytes) ----
#define W1A_OFF 0
#define W1A_B (256 * 256 * 2)
#define W1B_OFF (W1A_OFF + W1A_B)
#define W1B_B (128 * 256 * 2)
#define W2A_OFF (W1B_OFF + W1B_B)
#define W2A_B (256 * 384 * 2)
#define W2B_OFF (W2A_OFF + W2A_B)
#define W2B_B (128 * 256 * 2)
#define WEND (W2B_OFF + W2B_B)

#define NSCAN_BLOCKS ((NN + 255) / 256)
#define BASE_OFF WEND
#define BASE_B (((NN + 1 + 63) / 64) * 64 * 4)
#define BSUM_OFF (BASE_OFF + BASE_B)
#define BSUM_B (256 * 4)
#define OFF_OFF (BSUM_OFF + BSUM_B)
#define OFF_B (NN * 4)
#define CNT2_OFF (OFF_OFF + OFF_B)
#define CNT2_B (NN * 4)
#define PERM_OFF (CNT2_OFF + CNT2_B)
#define PERM_B (NE * 4)

// v4 path: P fp32 [50048][256] + hidden bf16 [NE][256]
#define NPAD 50048
#define P_OFF (((PERM_OFF + PERM_B) + 255) / 256 * 256)
#define P_B (NPAD * 256 * 4)
#define HID_OFF ((size_t)(((P_OFF + P_B) + 255) / 256 * 256))
#define HID_B ((size_t)NE * 256 * 2)
#define V4_NEED (HID_OFF + HID_B)

// round-3 fallback path: h bf16 [NE][128]
#define HBUF_OFF P_OFF
#define HBUF_B ((size_t)NE * 128 * 2)
#define CSR_NEED ((size_t)HBUF_OFF + HBUF_B)

// Convert W[k][n] (row-major fp32) -> Wt[n][k] bf16 (k contiguous).
__global__ __launch_bounds__(256) void transpose_bf16(
    const float* __restrict__ src, bf16_t* __restrict__ dst, int K, int Nn) {
  int idx = blockIdx.x * 256 + threadIdx.x;
  if (idx >= K * Nn) return;
  int n = idx / K;
  int k = idx - n * K;
  dst[idx] = (bf16_t)src[k * Nn + n];
}

// ================= CSR construction =================
__global__ __launch_bounds__(256) void hist_kernel(
    const int* __restrict__ ei, int* __restrict__ cnt) {
  int e = blockIdx.x * 256 + threadIdx.x;
  if (e < NE) atomicAdd(&cnt[ei[NE + e]], 1);
}

__global__ __launch_bounds__(256) void scan1(
    const int* __restrict__ cnt, int* __restrict__ base, int* __restrict__ bsum) {
  __shared__ int s[256];
  const int tid = threadIdx.x;
  const int g = blockIdx.x * 256 + tid;
  int v = (g < NN) ? cnt[g] : 0;
  s[tid] = v;
  __syncthreads();
#pragma unroll
  for (int o = 1; o < 256; o <<= 1) {
    int t = (tid >= o) ? s[tid - o] : 0;
    __syncthreads();
    s[tid] += t;
    __syncthreads();
  }
  if (g < NN) base[g] = s[tid] - v;
  if (tid == 255) bsum[blockIdx.x] = s[255];
}

__global__ __launch_bounds__(256) void scan2(int* __restrict__ bsum, int nb) {
  __shared__ int s[256];
  const int tid = threadIdx.x;
  int v = (tid < nb) ? bsum[tid] : 0;
  s[tid] = v;
  __syncthreads();
#pragma unroll
  for (int o = 1; o < 256; o <<= 1) {
    int t = (tid >= o) ? s[tid - o] : 0;
    __syncthreads();
    s[tid] += t;
    __syncthreads();
  }
  if (tid < nb) bsum[tid] = s[tid] - v;
}

__global__ __launch_bounds__(256) void scan3(
    int* __restrict__ base, const int* __restrict__ bsum, int* __restrict__ off) {
  int g = blockIdx.x * 256 + threadIdx.x;
  if (g < NN) {
    int b = base[g] + bsum[g >> 8];
    base[g] = b;
    off[g] = b;
  } else if (g == NN) {
    base[NN] = NE;
  }
}

__global__ __launch_bounds__(256) void slot_kernel(
    const int* __restrict__ ei, int* __restrict__ off, int* __restrict__ perm) {
  int e = blockIdx.x * 256 + threadIdx.x;
  if (e < NE) {
    int p = atomicAdd(&off[ei[NE + e]], 1);
    perm[p] = e;
  }
}

// ====== v4 kernel 1: P = x @ W1a_top + b1a (fp32 out, [NPAD][256]) ======
__global__ __launch_bounds__(256) void p_kernel(
    const float* __restrict__ x, const bf16_t* __restrict__ Wt1a,
    const float* __restrict__ b1a, float* __restrict__ P) {
  __shared__ __align__(16) bf16_t Ain[64][136];
  const int tid = threadIdx.x, lane = tid & 63, wave = tid >> 6;
  const int n0 = blockIdx.x * 64;

  for (int v = tid; v < 64 * 32; v += 256) {
    const int i = v >> 5, c0 = (v & 31) * 4;
    const int n = n0 + i;
    float4 f = make_float4(0.f, 0.f, 0.f, 0.f);
    if (n < NN) f = *(const float4*)(x + (size_t)n * 128 + c0);
    union { bf16_t h[4]; uint2 u; } pk;
    pk.h[0] = (bf16_t)f.x; pk.h[1] = (bf16_t)f.y;
    pk.h[2] = (bf16_t)f.z; pk.h[3] = (bf16_t)f.w;
    *(uint2*)&Ain[i][c0] = pk.u;
  }
  __syncthreads();

  const int lr = lane & 15, lq = lane >> 4;
  const int n_off = wave * 64;
  float bias1[4];
#pragma unroll
  for (int nt = 0; nt < 4; ++nt) bias1[nt] = b1a[n_off + nt * 16 + lr];

  f32x4 acc[4][4];
#pragma unroll
  for (int mt = 0; mt < 4; ++mt)
#pragma unroll
    for (int nt = 0; nt < 4; ++nt) acc[mt][nt] = (f32x4){0.f, 0.f, 0.f, 0.f};

#pragma unroll
  for (int ks = 0; ks < 4; ++ks) {
    const int k0 = ks * 32 + lq * 8;
    bf16x8 af[4], bv[4];
#pragma unroll
    for (int mt = 0; mt < 4; ++mt) af[mt] = *(const bf16x8*)&Ain[mt * 16 + lr][k0];
#pragma unroll
    for (int nt = 0; nt < 4; ++nt)
      bv[nt] = *(const bf16x8*)&Wt1a[(n_off + nt * 16 + lr) * 256 + k0];  // top half
#pragma unroll
    for (int mt = 0; mt < 4; ++mt)
#pragma unroll
      for (int nt = 0; nt < 4; ++nt)
        acc[mt][nt] = __builtin_amdgcn_mfma_f32_16x16x32_bf16(
            af[mt], bv[nt], acc[mt][nt], 0, 0, 0);
  }
  // direct fp32 store (rows < NPAD always)
#pragma unroll
  for (int mt = 0; mt < 4; ++mt)
#pragma unroll
    for (int nt = 0; nt < 4; ++nt) {
      const int colF = n_off + nt * 16 + lr;
#pragma unroll
      for (int r = 0; r < 4; ++r) {
        const int n = n0 + mt * 16 + lq * 4 + r;
        P[(size_t)n * 256 + colF] = acc[mt][nt][r] + bias1[nt];
      }
    }
}

// ====== v4 kernel 2: hid[e] = relu(ea@W1a_bot + P[row]) bf16 [NE][256] ======
__global__ __launch_bounds__(256) void edge_q_kernel(
    const float* __restrict__ ea, const int* __restrict__ ei,
    const bf16_t* __restrict__ Wt1a, const float* __restrict__ P,
    bf16_t* __restrict__ hid) {
  __shared__ __align__(16) bf16_t Ain[64][136];
  __shared__ __align__(16) bf16_t Aout[64][264];
  __shared__ int rowS[64];
  const int tid = threadIdx.x, lane = tid & 63, wave = tid >> 6;
  const int e0 = blockIdx.x * 64;

  if (tid < 64) rowS[tid] = ei[e0 + tid];
  for (int v = tid; v < 64 * 32; v += 256) {
    const int i = v >> 5, c0 = (v & 31) * 4;
    float4 f = *(const float4*)(ea + (size_t)(e0 + i) * 128 + c0);
    union { bf16_t h[4]; uint2 u; } pk;
    pk.h[0] = (bf16_t)f.x; pk.h[1] = (bf16_t)f.y;
    pk.h[2] = (bf16_t)f.z; pk.h[3] = (bf16_t)f.w;
    *(uint2*)&Ain[i][c0] = pk.u;
  }
  __syncthreads();

  const int lr = lane & 15, lq = lane >> 4;
  const int n_off = wave * 64;

  f32x4 acc[4][4];
#pragma unroll
  for (int mt = 0; mt < 4; ++mt)
#pragma unroll
    for (int nt = 0; nt < 4; ++nt) acc[mt][nt] = (f32x4){0.f, 0.f, 0.f, 0.f};

#pragma unroll
  for (int ks = 0; ks < 4; ++ks) {
    const int k0 = ks * 32 + lq * 8;
    bf16x8 af[4], bv[4];
#pragma unroll
    for (int mt = 0; mt < 4; ++mt) af[mt] = *(const bf16x8*)&Ain[mt * 16 + lr][k0];
#pragma unroll
    for (int nt = 0; nt < 4; ++nt)
      bv[nt] = *(const bf16x8*)&Wt1a[(n_off + nt * 16 + lr) * 256 + 128 + k0];  // bottom
#pragma unroll
    for (int mt = 0; mt < 4; ++mt)
#pragma unroll
      for (int nt = 0; nt < 4; ++nt)
        acc[mt][nt] = __builtin_amdgcn_mfma_f32_16x16x32_bf16(
            af[mt], bv[nt], acc[mt][nt], 0, 0, 0);
  }
  // C-layout scatter of Q into Aout
#pragma unroll
  for (int mt = 0; mt < 4; ++mt)
#pragma unroll
    for (int nt = 0; nt < 4; ++nt) {
      const int row = mt * 16 + lq * 4;
      const int colF = n_off + nt * 16 + lr;
#pragma unroll
      for (int r = 0; r < 4; ++r) Aout[row + r][colF] = (bf16_t)acc[mt][nt][r];
    }
  __syncthreads();

  // fused epilogue: hid = relu(Q + P[row]); coalesced 64B groups
  {
    const int i = tid >> 2, q = tid & 3;
    const float* Pr = P + (size_t)rowS[i] * 256;
    bf16_t* dst = hid + (size_t)(e0 + i) * 256;
#pragma unroll
    for (int c8 = 0; c8 < 8; ++c8) {
      const int c = c8 * 32 + q * 8;
      bf16x8 qv = *(const bf16x8*)&Aout[i][c];
      float4 p0 = *(const float4*)(Pr + c);
      float4 p1 = *(const float4*)(Pr + c + 4);
      float pv[8] = {p0.x, p0.y, p0.z, p0.w, p1.x, p1.y, p1.z, p1.w};
      bf16x8 o;
#pragma unroll
      for (int k = 0; k < 8; ++k)
        o[k] = (bf16_t)fmaxf((float)qv[k] + pv[k], 0.f);
      *(bf16x8*)(dst + c) = o;
    }
  }
}

// ====== v4 kernel 3: node — gather mean(hid), @W1b, then mlp2 ======
__global__ __launch_bounds__(256) void node_kernel(
    const float* __restrict__ x, const float* __restrict__ u,
    const int* __restrict__ batch,
    const bf16_t* __restrict__ Wt1b, const float* __restrict__ b1b,
    const bf16_t* __restrict__ Wt2a, const float* __restrict__ b2a,
    const bf16_t* __restrict__ Wt2b, const float* __restrict__ b2b,
    const bf16_t* __restrict__ hid, const int* __restrict__ base,
    const int* __restrict__ perm, float* __restrict__ out) {
  __shared__ __align__(16) bf16_t As[64][392];
  __shared__ int bS[64], bE[64];
  const int tid = threadIdx.x, lane = tid & 63, wave = tid >> 6;
  const int n0 = blockIdx.x * 64;

  if (tid < 64) {
    int n = n0 + tid;
    bS[tid] = (n < NN) ? base[n] : 0;
    bE[tid] = (n < NN) ? base[n + 1] : 0;
  }
  __syncthreads();

  // phase 1: A1 = mean of hid rows in bucket -> As cols 0..255 (bf16)
  {
    const int i = tid >> 2, q = tid & 3;
    float acc[64];
#pragma unroll
    for (int c = 0; c < 64; ++c) acc[c] = 0.f;
    const int jb = bS[i], je = bE[i];
    for (int j = jb; j < je; ++j) {
      const int e = perm[j];
      if ((unsigned)e >= NE) continue;
      const bf16x8* hp = (const bf16x8*)(hid + (size_t)e * 256 + q * 64);
#pragma unroll
      for (int v = 0; v < 8; ++v) {
        bf16x8 hv = hp[v];
#pragma unroll
        for (int c = 0; c < 8; ++c) acc[v * 8 + c] += (float)hv[c];
      }
    }
    const float inv = 1.0f / fmaxf((float)(je - jb), 1.0f);
#pragma unroll
    for (int c = 0; c < 64; c += 4) {
      union { bf16_t h[4]; uint2 uu; } pk;
      pk.h[0] = (bf16_t)(acc[c] * inv);
      pk.h[1] = (bf16_t)(acc[c + 1] * inv);
      pk.h[2] = (bf16_t)(acc[c + 2] * inv);
      pk.h[3] = (bf16_t)(acc[c + 3] * inv);
      *(uint2*)&As[i][q * 64 + c] = pk.uu;
    }
  }
  __syncthreads();

  const int lr = lane & 15, lq = lane >> 4;

  // phase 2: agg = A1 @ W1b + b1b*[cnt>0] ; wave owns 32 cols of N=128
  const int n2 = wave * 32;
  float bias1b[2];
#pragma unroll
  for (int nt = 0; nt < 2; ++nt) bias1b[nt] = b1b[n2 + nt * 16 + lr];

  f32x4 accB[4][2];
#pragma unroll
  for (int mt = 0; mt < 4; ++mt)
#pragma unroll
    for (int nt = 0; nt < 2; ++nt) accB[mt][nt] = (f32x4){0.f, 0.f, 0.f, 0.f};

#pragma unroll
  for (int ks = 0; ks < 8; ++ks) {
    const int k0 = ks * 32 + lq * 8;
    bf16x8 af[4], bv[2];
#pragma unroll
    for (int mt = 0; mt < 4; ++mt) af[mt] = *(const bf16x8*)&As[mt * 16 + lr][k0];
#pragma unroll
    for (int nt = 0; nt < 2; ++nt)
      bv[nt] = *(const bf16x8*)&Wt1b[(n2 + nt * 16 + lr) * 256 + k0];
#pragma unroll
    for (int mt = 0; mt < 4; ++mt)
#pragma unroll
      for (int nt = 0; nt < 2; ++nt)
        accB[mt][nt] = __builtin_amdgcn_mfma_f32_16x16x32_bf16(
            af[mt], bv[nt], accB[mt][nt], 0, 0, 0);
  }
  __syncthreads();  // all A1 reads done before As is overwritten

  // write agg -> As cols 128..255 (conditional bias for empty buckets)
#pragma unroll
  for (int mt = 0; mt < 4; ++mt)
#pragma unroll
    for (int nt = 0; nt < 2; ++nt) {
      const int colF = n2 + nt * 16 + lr;
#pragma unroll
      for (int r = 0; r < 4; ++r) {
        const int row = mt * 16 + lq * 4 + r;
        const float bb = (bE[row] > bS[row]) ? bias1b[nt] : 0.f;
        As[row][128 + colF] = (bf16_t)(accB[mt][nt][r] + bb);
      }
    }
  // stage x (cols 0..127) and u[batch] (cols 256..383)
  for (int v = tid; v < 64 * 32; v += 256) {
    const int i = v >> 5, c0 = (v & 31) * 4;
    const int n = n0 + i;
    float4 f = make_float4(0.f, 0.f, 0.f, 0.f);
    if (n < NN) f = *(const float4*)(x + (size_t)n * 128 + c0);
    union { bf16_t h[4]; uint2 uu; } pk;
    pk.h[0] = (bf16_t)f.x; pk.h[1] = (bf16_t)f.y;
    pk.h[2] = (bf16_t)f.z; pk.h[3] = (bf16_t)f.w;
    *(uint2*)&As[i][c0] = pk.uu;
  }
  for (int v = tid; v < 64 * 32; v += 256) {
    const int i = v >> 5, c0 = (v & 31) * 4;
    const int n = n0 + i;
    float4 f = make_float4(0.f, 0.f, 0.f, 0.f);
    if (n < NN) f = *(const float4*)(u + (size_t)batch[n] * 128 + c0);
    union { bf16_t h[4]; uint2 uu; } pk;
    pk.h[0] = (bf16_t)f.x; pk.h[1] = (bf16_t)f.y;
    pk.h[2] = (bf16_t)f.z; pk.h[3] = (bf16_t)f.w;
    *(uint2*)&As[i][256 + c0] = pk.uu;
  }
  __syncthreads();

  // phase 3: mlp2 layer 1: hidden(64x256) = relu(z @ W2a + b2a)
  const int n_off = wave * 64;
  float bias1[4];
#pragma unroll
  for (int nt = 0; nt < 4; ++nt) bias1[nt] = b2a[n_off + nt * 16 + lr];

  f32x4 acc[4][4];
#pragma unroll
  for (int mt = 0; mt < 4; ++mt)
#pragma unroll
    for (int nt = 0; nt < 4; ++nt) acc[mt][nt] = (f32x4){0.f, 0.f, 0.f, 0.f};

#pragma unroll
  for (int ks = 0; ks < 12; ++ks) {
    const int k0 = ks * 32 + lq * 8;
    bf16x8 af[4], bv[4];
#pragma unroll
    for (int mt = 0; mt < 4; ++mt) af[mt] = *(const bf16x8*)&As[mt * 16 + lr][k0];
#pragma unroll
    for (int nt = 0; nt < 4; ++nt)
      bv[nt] = *(const bf16x8*)&Wt2a[(n_off + nt * 16 + lr) * 384 + k0];
#pragma unroll
    for (int mt = 0; mt < 4; ++mt)
#pragma unroll
      for (int nt = 0; nt < 4; ++nt)
        acc[mt][nt] = __builtin_amdgcn_mfma_f32_16x16x32_bf16(
            af[mt], bv[nt], acc[mt][nt], 0, 0, 0);
  }
  __syncthreads();
#pragma unroll
  for (int mt = 0; mt < 4; ++mt)
#pragma unroll
    for (int nt = 0; nt < 4; ++nt) {
      const int row = mt * 16 + lq * 4;
      const int colF = n_off + nt * 16 + lr;
#pragma unroll
      for (int r = 0; r < 4; ++r) {
        float v = acc[mt][nt][r] + bias1[nt];
        As[row + r][colF] = (bf16_t)fmaxf(v, 0.f);
      }
    }
  __syncthreads();

  // mlp2 layer 2: out(64x128) = hidden @ W2b + b2b
  float bias2[2];
#pragma unroll
  for (int nt = 0; nt < 2; ++nt) bias2[nt] = b2b[n2 + nt * 16 + lr];

  f32x4 acc2[4][2];
#pragma unroll
  for (int mt = 0; mt < 4; ++mt)
#pragma unroll
    for (int nt = 0; nt < 2; ++nt) acc2[mt][nt] = (f32x4){0.f, 0.f, 0.f, 0.f};

#pragma unroll
  for (int ks = 0; ks < 8; ++ks) {
    const int k0 = ks * 32 + lq * 8;
    bf16x8 af[4], bv[2];
#pragma unroll
    for (int mt = 0; mt < 4; ++mt) af[mt] = *(const bf16x8*)&As[mt * 16 + lr][k0];
#pragma unroll
    for (int nt = 0; nt < 2; ++nt)
      bv[nt] = *(const bf16x8*)&Wt2b[(n2 + nt * 16 + lr) * 256 + k0];
#pragma unroll
    for (int mt = 0; mt < 4; ++mt)
#pragma unroll
      for (int nt = 0; nt < 2; ++nt)
        acc2[mt][nt] = __builtin_amdgcn_mfma_f32_16x16x32_bf16(
            af[mt], bv[nt], acc2[mt][nt], 0, 0, 0);
  }

#pragma unroll
  for (int mt = 0; mt < 4; ++mt)
#pragma unroll
    for (int nt = 0; nt < 2; ++nt) {
      const int colF = n2 + nt * 16 + lr;
#pragma unroll
      for (int r = 0; r < 4; ++r) {
        const int row = mt * 16 + lq * 4 + r;
        const int n = n0 + row;
        if (n < NN) out[(size_t)n * 128 + colF] = acc2[mt][nt][r] + bias2[nt];
      }
    }
}

// ================= round-3 fallback kernels (proven) =================
__global__ __launch_bounds__(256) void edge_mlp_csr(
    const float* __restrict__ x, const int* __restrict__ ei,
    const float* __restrict__ ea,
    const bf16_t* __restrict__ Wt1a, const float* __restrict__ b1a,
    const bf16_t* __restrict__ Wt1b, const float* __restrict__ b1b,
    bf16_t* __restrict__ hbuf) {
  __shared__ __align__(16) bf16_t As[64][264];
  __shared__ int rowS[64];
  const int tid = threadIdx.x;
  const int lane = tid & 63;
  const int wave = tid >> 6;
  const int e0 = blockIdx.x * 64;

  if (tid < 64) rowS[tid] = ei[e0 + tid];
  __syncthreads();
  {
    const int t_in = tid & 63;
    const int esub = tid >> 6;
    const int c0 = t_in * 4;
#pragma unroll
    for (int it = 0; it < 16; ++it) {
      const int i = it * 4 + esub;
      float4 f;
      if (c0 < 128) f = *(const float4*)(x + rowS[i] * 128 + c0);
      else f = *(const float4*)(ea + (e0 + i) * 128 + (c0 - 128));
      union { bf16_t h[4]; uint2 u; } pk;
      pk.h[0] = (bf16_t)f.x; pk.h[1] = (bf16_t)f.y;
      pk.h[2] = (bf16_t)f.z; pk.h[3] = (bf16_t)f.w;
      *(uint2*)&As[i][c0] = pk.u;
    }
  }
  __syncthreads();
  const int lr = lane & 15;
  const int lq = lane >> 4;
  const int n_off = wave * 64;
  float bias1[4];
#pragma unroll
  for (int nt = 0; nt < 4; ++nt) bias1[nt] = b1a[n_off + nt * 16 + lr];
  f32x4 acc[4][4];
#pragma unroll
  for (int mt = 0; mt < 4; ++mt)
#pragma unroll
    for (int nt = 0; nt < 4; ++nt) acc[mt][nt] = (f32x4){0.f, 0.f, 0.f, 0.f};
#pragma unroll
  for (int ks = 0; ks < 8; ++ks) {
    const int k0 = ks * 32 + lq * 8;
    bf16x8 af[4], bv[4];
#pragma unroll
    for (int mt = 0; mt < 4; ++mt) af[mt] = *(const bf16x8*)&As[mt * 16 + lr][k0];
#pragma unroll
    for (int nt = 0; nt < 4; ++nt)
      bv[nt] = *(const bf16x8*)&Wt1a[(n_off + nt * 16 + lr) * 256 + k0];
#pragma unroll
    for (int mt = 0; mt < 4; ++mt)
#pragma unroll
      for (int nt = 0; nt < 4; ++nt)
        acc[mt][nt] = __builtin_amdgcn_mfma_f32_16x16x32_bf16(
            af[mt], bv[nt], acc[mt][nt], 0, 0, 0);
  }
  __syncthreads();
#pragma unroll
  for (int mt = 0; mt < 4; ++mt)
#pragma unroll
    for (int nt = 0; nt < 4; ++nt) {
      const int row = mt * 16 + lq * 4;
      const int colF = n_off + nt * 16 + lr;
#pragma unroll
      for (int r = 0; r < 4; ++r) {
        float v = acc[mt][nt][r] + bias1[nt];
        As[row + r][colF] = (bf16_t)fmaxf(v, 0.f);
      }
    }
  __syncthreads();
  const int n2 = wave * 32;
  float bias2[2];
#pragma unroll
  for (int nt = 0; nt < 2; ++nt) bias2[nt] = b1b[n2 + nt * 16 + lr];
  f32x4 acc2[4][2];
#pragma unroll
  for (int mt = 0; mt < 4; ++mt)
#pragma unroll
    for (int nt = 0; nt < 2; ++nt) acc2[mt][nt] = (f32x4){0.f, 0.f, 0.f, 0.f};
#pragma unroll
  for (int ks = 0; ks < 8; ++ks) {
    const int k0 = ks * 32 + lq * 8;
    bf16x8 af[4], bv[2];
#pragma unroll
    for (int mt = 0; mt < 4; ++mt) af[mt] = *(const bf16x8*)&As[mt * 16 + lr][k0];
#pragma unroll
    for (int nt = 0; nt < 2; ++nt)
      bv[nt] = *(const bf16x8*)&Wt1b[(n2 + nt * 16 + lr) * 256 + k0];
#pragma unroll
    for (int mt = 0; mt < 4; ++mt)
#pragma unroll
      for (int nt = 0; nt < 2; ++nt)
        acc2[mt][nt] = __builtin_amdgcn_mfma_f32_16x16x32_bf16(
            af[mt], bv[nt], acc2[mt][nt], 0, 0, 0);
  }
  __syncthreads();
#pragma unroll
  for (int mt = 0; mt < 4; ++mt)
#pragma unroll
    for (int nt = 0; nt < 2; ++nt) {
      const int colF = n2 + nt * 16 + lr;
#pragma unroll
      for (int r = 0; r < 4; ++r) {
        const int row = mt * 16 + lq * 4 + r;
        As[row][colF] = (bf16_t)(acc2[mt][nt][r] + bias2[nt]);
      }
    }
  __syncthreads();
  {
    const int i = tid >> 2;
    const int q = tid & 3;
    const uint4* src = (const uint4*)&As[i][q * 32];
    uint4* dst = (uint4*)(hbuf + (size_t)(e0 + i) * 128 + q * 32);
    uint4 a0 = src[0], a1 = src[1], a2 = src[2], a3 = src[3];
    dst[0] = a0; dst[1] = a1; dst[2] = a2; dst[3] = a3;
  }
}

__global__ __launch_bounds__(256) void node_mlp_csr(
    const float* __restrict__ x, const float* __restrict__ u,
    const int* __restrict__ batch,
    const bf16_t* __restrict__ Wt2a, const float* __restrict__ b2a,
    const bf16_t* __restrict__ Wt2b, const float* __restrict__ b2b,
    const bf16_t* __restrict__ hbuf, const int* __restrict__ base,
    const int* __restrict__ perm, float* __restrict__ out) {
  __shared__ __align__(16) bf16_t As[64][392];
  __shared__ int bS[64], bE[64];
  const int tid = threadIdx.x;
  const int lane = tid & 63;
  const int wave = tid >> 6;
  const int n0 = blockIdx.x * 64;

  if (tid < 64) {
    int n = n0 + tid;
    bS[tid] = (n < NN) ? base[n] : 0;
    bE[tid] = (n < NN) ? base[n + 1] : 0;
  }
  __syncthreads();
  for (int v = tid; v < 64 * 32; v += 256) {
    const int i = v >> 5;
    const int c0 = (v & 31) * 4;
    const int n = n0 + i;
    float4 f = make_float4(0.f, 0.f, 0.f, 0.f);
    if (n < NN) f = *(const float4*)(x + n * 128 + c0);
    union { bf16_t h[4]; uint2 uu; } pk;
    pk.h[0] = (bf16_t)f.x; pk.h[1] = (bf16_t)f.y;
    pk.h[2] = (bf16_t)f.z; pk.h[3] = (bf16_t)f.w;
    *(uint2*)&As[i][c0] = pk.uu;
  }
  for (int v = tid; v < 64 * 32; v += 256) {
    const int i = v >> 5;
    const int c0 = (v & 31) * 4;
    const int n = n0 + i;
    float4 f = make_float4(0.f, 0.f, 0.f, 0.f);
    if (n < NN) f = *(const float4*)(u + batch[n] * 128 + c0);
    union { bf16_t h[4]; uint2 uu; } pk;
    pk.h[0] = (bf16_t)f.x; pk.h[1] = (bf16_t)f.y;
    pk.h[2] = (bf16_t)f.z; pk.h[3] = (bf16_t)f.w;
    *(uint2*)&As[i][256 + c0] = pk.uu;
  }
  {
    const int i = tid >> 2;
    const int q = tid & 3;
    float acc[32];
#pragma unroll
    for (int c = 0; c < 32; ++c) acc[c] = 0.f;
    const int jb = bS[i], je = bE[i];
    for (int j = jb; j < je; ++j) {
      const int e = perm[j];
      if ((unsigned)e >= NE) continue;
      const bf16x8* hp = (const bf16x8*)(hbuf + (size_t)e * 128 + q * 32);
#pragma unroll
      for (int v = 0; v < 4; ++v) {
        bf16x8 hv = hp[v];
#pragma unroll
        for (int c = 0; c < 8; ++c) acc[v * 8 + c] += (float)hv[c];
      }
    }
    const float inv = 1.0f / fmaxf((float)(je - jb), 1.0f);
#pragma unroll
    for (int c = 0; c < 32; ++c)
      As[i][128 + q * 32 + c] = (bf16_t)(acc[c] * inv);
  }
  __syncthreads();

  const int lr = lane & 15;
  const int lq = lane >> 4;
  const int n_off = wave * 64;
  float bias1[4];
#pragma unroll
  for (int nt = 0; nt < 4; ++nt) bias1[nt] = b2a[n_off + nt * 16 + lr];
  f32x4 acc[4][4];
#pragma unroll
  for (int mt = 0; mt < 4; ++mt)
#pragma unroll
    for (int nt = 0; nt < 4; ++nt) acc[mt][nt] = (f32x4){0.f, 0.f, 0.f, 0.f};
#pragma unroll
  for (int ks = 0; ks < 12; ++ks) {
    const int k0 = ks * 32 + lq * 8;
    bf16x8 af[4], bv[4];
#pragma unroll
    for (int mt = 0; mt < 4; ++mt) af[mt] = *(const bf16x8*)&As[mt * 16 + lr][k0];
#pragma unroll
    for (int nt = 0; nt < 4; ++nt)
      bv[nt] = *(const bf16x8*)&Wt2a[(n_off + nt * 16 + lr) * 384 + k0];
#pragma unroll
    for (int mt = 0; mt < 4; ++mt)
#pragma unroll
      for (int nt = 0; nt < 4; ++nt)
        acc[mt][nt] = __builtin_amdgcn_mfma_f32_16x16x32_bf16(
            af[mt], bv[nt], acc[mt][nt], 0, 0, 0);
  }
  __syncthreads();
#pragma unroll
  for (int mt = 0; mt < 4; ++mt)
#pragma unroll
    for (int nt = 0; nt < 4; ++nt) {
      const int row = mt * 16 + lq * 4;
      const int colF = n_off + nt * 16 + lr;
#pragma unroll
      for (int r = 0; r < 4; ++r) {
        float v = acc[mt][nt][r] + bias1[nt];
        As[row + r][colF] = (bf16_t)fmaxf(v, 0.f);
      }
    }
  __syncthreads();
  const int n2 = wave * 32;
  float bias2[2];
#pragma unroll
  for (int nt = 0; nt < 2; ++nt) bias2[nt] = b2b[n2 + nt * 16 + lr];
  f32x4 acc2[4][2];
#pragma unroll
  for (int mt = 0; mt < 4; ++mt)
#pragma unroll
    for (int nt = 0; nt < 2; ++nt) acc2[mt][nt] = (f32x4){0.f, 0.f, 0.f, 0.f};
#pragma unroll
  for (int ks = 0; ks < 8; ++ks) {
    const int k0 = ks * 32 + lq * 8;
    bf16x8 af[4], bv[2];
#pragma unroll
    for (int mt = 0; mt < 4; ++mt) af[mt] = *(const bf16x8*)&As[mt * 16 + lr][k0];
#pragma unroll
    for (int nt = 0; nt < 2; ++nt)
      bv[nt] = *(const bf16x8*)&Wt2b[(n2 + nt * 16 + lr) * 256 + k0];
#pragma unroll
    for (int mt = 0; mt < 4; ++mt)
#pragma unroll
      for (int nt = 0; nt < 2; ++nt)
        acc2[mt][nt] = __builtin_amdgcn_mfma_f32_16x16x32_bf16(
            af[mt], bv[nt], acc2[mt][nt], 0, 0, 0);
  }
#pragma unroll
  for (int mt = 0; mt < 4; ++mt)
#pragma unroll
    for (int nt = 0; nt < 2; ++nt) {
      const int colF = n2 + nt * 16 + lr;
#pragma unroll
      for (int r = 0; r < 4; ++r) {
        const int row = mt * 16 + lq * 4 + r;
        const int n = n0 + row;
        if (n < NN) out[n * 128 + colF] = acc2[mt][nt][r] + bias2[nt];
      }
    }
}

extern "C" void kernel_launch(void* const* d_in, const int* in_sizes, int n_in,
                              void* d_out, int out_size, void* d_ws, size_t ws_size,
                              hipStream_t stream) {
  const float* x    = (const float*)d_in[0];
  const int*   ei   = (const int*)d_in[1];
  const float* ea   = (const float*)d_in[2];
  const float* u    = (const float*)d_in[3];
  const int*   batch= (const int*)d_in[4];
  const float* W1a  = (const float*)d_in[5];
  const float* b1a  = (const float*)d_in[6];
  const float* W1b  = (const float*)d_in[7];
  const float* b1b  = (const float*)d_in[8];
  const float* W2a  = (const float*)d_in[9];
  const float* b2a  = (const float*)d_in[10];
  const float* W2b  = (const float*)d_in[11];
  const float* b2b  = (const float*)d_in[12];

  char* ws = (char*)d_ws;
  bf16_t* w1a = (bf16_t*)(ws + W1A_OFF);
  bf16_t* w1b = (bf16_t*)(ws + W1B_OFF);
  bf16_t* w2a = (bf16_t*)(ws + W2A_OFF);
  bf16_t* w2b = (bf16_t*)(ws + W2B_OFF);

  transpose_bf16<<<256, 256, 0, stream>>>(W1a, w1a, 256, 256);
  transpose_bf16<<<128, 256, 0, stream>>>(W1b, w1b, 256, 128);
  transpose_bf16<<<384, 256, 0, stream>>>(W2a, w2a, 384, 256);
  transpose_bf16<<<128, 256, 0, stream>>>(W2b, w2b, 256, 128);

  int* base = (int*)(ws + BASE_OFF);
  int* bsum = (int*)(ws + BSUM_OFF);
  int* off  = (int*)(ws + OFF_OFF);
  int* cnt  = (int*)(ws + CNT2_OFF);
  int* perm = (int*)(ws + PERM_OFF);

  hipMemsetAsync(cnt, 0, CNT2_B, stream);
  hist_kernel<<<(NE + 255) / 256, 256, 0, stream>>>(ei, cnt);
  scan1<<<NSCAN_BLOCKS, 256, 0, stream>>>(cnt, base, bsum);
  scan2<<<1, 256, 0, stream>>>(bsum, NSCAN_BLOCKS);
  scan3<<<(NN + 256) / 256, 256, 0, stream>>>(base, bsum, off);
  slot_kernel<<<(NE + 255) / 256, 256, 0, stream>>>(ei, off, perm);

  if (ws_size >= V4_NEED) {
    float* P = (float*)(ws + P_OFF);
    bf16_t* hid = (bf16_t*)(ws + HID_OFF);
    p_kernel<<<(NN + 63) / 64, 256, 0, stream>>>(x, w1a, b1a, P);
    edge_q_kernel<<<NE / 64, 256, 0, stream>>>(ea, ei, w1a, P, hid);
    node_kernel<<<(NN + 63) / 64, 256, 0, stream>>>(
        x, u, batch, w1b, b1b, w2a, b2a, w2b, b2b, hid, base, perm,
        (float*)d_out);
  } else {
    bf16_t* hbuf = (bf16_t*)(ws + HBUF_OFF);
    edge_mlp_csr<<<NE / 64, 256, 0, stream>>>(x, ei, ea, w1a, b1a, w1b, b1b, hbuf);
    node_mlp_csr<<<(NN + 63) / 64, 256, 0, stream>>>(
        x, u, batch, w2a, b2a, w2b, b2b, hbuf, base, perm, (float*)d_out);
  }
}